// Round 3
// baseline (172.569 us; speedup 1.0000x reference)
//
#include <hip/hip_runtime.h>
#include <math.h>

#define NB 64
#define NP 8396
#define NK 6
#define NC 25
#define NPR 3            // NEG_POS_RATIO
#define MARKER 0x007FFFFFu   // fmap(-inf): positives' mining key; all finite scores map strictly above
#define BGROUP 16        // batches per k_iou block
#define CT 128           // k_conf tile (threads & priors per block)

// order-preserving float->uint map (for selecting the T-th largest)
__device__ inline unsigned fmap(float f){
    unsigned b = __float_as_uint(f);
    return (b & 0x80000000u) ? ~b : (b | 0x80000000u);
}

// ---------------- Kernel A: IoU, thread-per-prior, loop over batches ----------------
// grid = (ceil(NP/256), NB/BGROUP); priors in registers, gt in LDS.
// packed[b] = max over p of (iou_bits<<32 | ~p)  -> max iou with min index
__global__ __launch_bounds__(256) void k_iou(
    const float* __restrict__ prior, const float* __restrict__ gtr,
    float* __restrict__ iou,
    unsigned long long* __restrict__ packed, int* __restrict__ cnt)
{
    int p = blockIdx.x * 256 + threadIdx.x;
    int b0 = blockIdx.y * BGROUP;
    bool valid = p < NP;

    __shared__ float sgt[BGROUP * 25];
    for (int i = threadIdx.x; i < BGROUP * 25; i += 256)
        sgt[i] = gtr[b0 * 25 + i];

    float prx[24];
    float pa[NK];
    if (valid) {
        const float4* pr4 = (const float4*)(prior + p * 24);   // 96B rows, 16B aligned
#pragma unroll
        for (int i = 0; i < 6; i++) {
            float4 t = pr4[i];
            prx[4*i+0] = t.x; prx[4*i+1] = t.y; prx[4*i+2] = t.z; prx[4*i+3] = t.w;
        }
#pragma unroll
        for (int k = 0; k < NK; k++)
            pa[k] = (prx[4*k+2] - prx[4*k+0]) * (prx[4*k+3] - prx[4*k+1]);
    }
    __syncthreads();

    int lane = threadIdx.x & 63;
    for (int bb = 0; bb < BGROUP; ++bb) {
        int b = b0 + bb;
        const float* gt = &sgt[bb * 25 + 1];
        float v = 0.f;
        if (valid) {
            float csum = 0.f, fsum = 0.f;
#pragma unroll
            for (int k = 0; k < NK; k++) {
                float gx0 = gt[4*k+0], gy0 = gt[4*k+1], gx1 = gt[4*k+2], gy1 = gt[4*k+3];
                float ix = fminf(prx[4*k+2], gx1) - fmaxf(prx[4*k+0], gx0);
                float iy = fminf(prx[4*k+3], gy1) - fmaxf(prx[4*k+1], gy0);
                float cross = fmaxf(ix, 0.f) * fmaxf(iy, 0.f);
                float ga = (gx1 - gx0) * (gy1 - gy0);
                csum += cross;
                fsum += cross / (ga + pa[k] - cross);
            }
            v = (csum > 0.f) ? (fsum * (1.f / (float)NK)) : 0.f;
            iou[(size_t)b * NP + p] = v;
        }
        unsigned long long pk = valid
            ? (((unsigned long long)__float_as_uint(v) << 32) |
               (unsigned long long)(0xFFFFFFFFu - (unsigned)p))
            : 0ULL;
#pragma unroll
        for (int o = 32; o > 0; o >>= 1) {
            unsigned long long other = __shfl_down(pk, o);
            if (other > pk) pk = other;
        }
        unsigned long long bal = __ballot(valid && v >= 0.5f);
        if (lane == 0) {
            atomicMax(&packed[b], pk);
            int c = __popcll(bal);
            if (c) atomicAdd(&cnt[b], c);
        }
    }
}

// ---------------- Kernel B: unpack best, compute npos and Ntot (1 wave) ----------------
__global__ void k_mini(
    const unsigned long long* __restrict__ packed, const int* __restrict__ cnt,
    const float* __restrict__ iou,
    int* __restrict__ best, int* __restrict__ npos, int* __restrict__ Ntot)
{
    int b = threadIdx.x;   // 64 threads = NB
    unsigned long long pk = packed[b];
    int bst = (int)(0xFFFFFFFFu - (unsigned)(pk & 0xFFFFFFFFULL));
    int np = cnt[b] + ((iou[(size_t)b * NP + bst] >= 0.5f) ? 0 : 1);
    best[b] = bst;
    npos[b] = np;
    int s = np;
#pragma unroll
    for (int o = 32; o > 0; o >>= 1) s += __shfl_down(s, o);
    if (b == 0) *Ntot = s;
}

// ---------------- Kernel C: softmax CE + mining key + smooth-L1 (LDS-staged conf) ----------------
// grid = (ceil(NP/CT), NB), block = CT
__global__ __launch_bounds__(CT) void k_conf(
    const float* __restrict__ loc, const float* __restrict__ conf,
    const float* __restrict__ prior, const float* __restrict__ gtr,
    const float* __restrict__ iou, const int* __restrict__ best,
    unsigned* __restrict__ u, float* __restrict__ ce, float* __restrict__ llsum)
{
    int b = blockIdx.y;
    int p0 = blockIdx.x * CT;
    int rows = NP - p0; if (rows > CT) rows = CT;

    __shared__ float scf[CT * NC];   // 12.8 KB
    const float* gsrc = conf + ((size_t)b * NP + p0) * NC;
    int n = rows * NC;
    int n4 = n >> 2;
    const float4* g4 = (const float4*)gsrc;   // base offset is 16B-aligned (CT*NC*4 and NP*NC*4 are)
    float4* s4 = (float4*)scf;
    for (int i = threadIdx.x; i < n4; i += CT) s4[i] = g4[i];
    for (int i = (n4 << 2) + threadIdx.x; i < n; i += CT) scf[i] = gsrc[i];
    __syncthreads();

    int t = threadIdx.x;
    if (t >= rows) return;
    int p = p0 + t;
    size_t idx = (size_t)b * NP + p;
    bool pos = (iou[idx] >= 0.5f) || (p == best[b]);
    int cls = (int)gtr[b * 25];
    int tgt = pos ? cls : 0;

    const float* cf = scf + t * NC;   // 25*lane mod 32 is a bijection -> conflict-free
    float m = cf[0];
#pragma unroll
    for (int c = 1; c < NC; c++) m = fmaxf(m, cf[c]);
    float s = 0.f;
#pragma unroll
    for (int c = 0; c < NC; c++) s += expf(cf[c] - m);
    float xt = cf[tgt];
    float cev = m + logf(s) - xt;
    ce[idx] = cev;
    float pt = expf(xt - m) / s;
    float tl = -logf(pt + 1e-6f);
    u[idx] = pos ? MARKER : fmap(tl);

    if (pos) {
        const float* pr = prior + p * 24;
        const float* gt = gtr + b * 25 + 1;
        const float* lp = loc + idx * 24;
        float sum = 0.f;
#pragma unroll
        for (int k = 0; k < NK; k++) {
            float px0 = pr[4*k+0], py0 = pr[4*k+1], px1 = pr[4*k+2], py1 = pr[4*k+3];
            float gx0 = gt[4*k+0], gy0 = gt[4*k+1], gx1 = gt[4*k+2], gy1 = gt[4*k+3];
            float pcx = (px0 + px1) * 0.5f, pcy = (py0 + py1) * 0.5f;
            float pw = px1 - px0, ph = py1 - py0;
            float gcx = (gx0 + gx1) * 0.5f, gcy = (gy0 + gy1) * 0.5f;
            float gw = gx1 - gx0, gh = gy1 - gy0;
            float e0 = ((gcx - pcx) / pw) * 10.f;
            float e1 = ((gcy - pcy) / ph) * 10.f;
            float e2 = logf(gw / pw) * 5.f;
            float e3 = logf(gh / ph) * 5.f;
            float d;
            d = fabsf(lp[4*k+0] - e0); sum += (d < 1.f) ? 0.5f*d*d : d - 0.5f;
            d = fabsf(lp[4*k+1] - e1); sum += (d < 1.f) ? 0.5f*d*d : d - 0.5f;
            d = fabsf(lp[4*k+2] - e2); sum += (d < 1.f) ? 0.5f*d*d : d - 0.5f;
            d = fabsf(lp[4*k+3] - e3); sum += (d < 1.f) ? 0.5f*d*d : d - 0.5f;
        }
        atomicAdd(llsum, sum);
    }
}

// ---------------- Kernel D: LDS-resident byte-histogram top-T select + CE sum ----------------
__global__ __launch_bounds__(512) void k_select(
    const unsigned* __restrict__ u, const float* __restrict__ ce,
    const int* __restrict__ npos,
    float* __restrict__ cesum, int* __restrict__ selc)
{
    int b = blockIdx.x, tid = threadIdx.x;
    const unsigned* ub = u + (size_t)b * NP;
    const float* ceb = ce + (size_t)b * NP;

    __shared__ unsigned su[NP];     // 33.6 KB
    __shared__ int hist[256];
    __shared__ int sc[512];
    __shared__ float sf[512];
    __shared__ unsigned s_prefix;
    __shared__ int s_remain;
    __shared__ int s_cutoff;

    {   // coalesced uint4 fill (NP = 4*2099 exactly)
        const uint4* g4 = (const uint4*)ub;
        uint4* s4 = (uint4*)su;
        for (int i = tid; i < NP / 4; i += 512) s4[i] = g4[i];
    }
    int np = npos[b];
    int T = NPR * np;
    if (T > NP - np) T = NP - np;
    if (tid == 0) { s_prefix = 0u; s_remain = T; }
    __syncthreads();

    // 4 byte-levels, MSB first: find T-th largest key (exact)
#pragma unroll
    for (int level = 0; level < 4; ++level) {
        const int shift = 24 - 8 * level;
        if (tid < 256) hist[tid] = 0;
        __syncthreads();
        unsigned pref = s_prefix;
        int remain = s_remain;
        for (int p = tid; p < NP; p += 512) {
            unsigned v = su[p];
            bool match = (level == 0) || ((v >> (shift + 8)) == pref);
            if (match) atomicAdd(&hist[(v >> shift) & 255], 1);
        }
        __syncthreads();
        if (tid < 64) {   // single-wave suffix scan: lane owns bins [4t..4t+3]
            int h0 = hist[4*tid+0], h1 = hist[4*tid+1], h2 = hist[4*tid+2], h3 = hist[4*tid+3];
            int loc = h0 + h1 + h2 + h3;
            int run = loc;
#pragma unroll
            for (int o = 1; o < 64; o <<= 1) {
                int oth = __shfl_down(run, o);
                if (tid + o < 64) run += oth;
            }
            int suff = run - loc;   // sum over lanes > tid
            int hh[4] = {h0, h1, h2, h3};
#pragma unroll
            for (int j = 3; j >= 0; --j) {
                int above = suff, hj = hh[j];
                if (above < remain && above + hj >= remain) {   // exactly one (tid,j)
                    s_prefix = (pref << 8) | (unsigned)(4*tid + j);
                    s_remain = remain - above;
                }
                suff += hj;
            }
        }
        __syncthreads();
    }
    unsigned thr = s_prefix;
    int needed = s_remain;   // boundary ties to take, ascending index order

    // count ties
    int tc = 0;
    for (int p = tid; p < NP; p += 512) tc += (su[p] == thr) ? 1 : 0;
    sc[tid] = tc;
    __syncthreads();
    for (int s = 256; s > 0; s >>= 1) { if (tid < s) sc[tid] += sc[tid + s]; __syncthreads(); }
    if (tid == 0) {
        int total_ties = sc[0];
        if (total_ties <= needed) s_cutoff = NP;     // take all ties
        else {                                        // rare: stable prefix by index
            int c2 = 0, cut = -1;
            for (int p = 0; p < NP; ++p)
                if (su[p] == thr) { if (++c2 == needed) { cut = p; break; } }
            s_cutoff = cut;
        }
    }
    __syncthreads();
    int cutoff = s_cutoff;

    // sum CE over positives (MARKER) + selected negatives
    float sum = 0.f;
    for (int p = tid; p < NP; p += 512) {
        unsigned v = su[p];
        bool take = (v == MARKER) || (v > thr) || ((v == thr) && (p <= cutoff));
        if (take) sum += ceb[p];
    }
    sf[tid] = sum;
    __syncthreads();
    for (int s = 256; s > 0; s >>= 1) { if (tid < s) sf[tid] += sf[tid + s]; __syncthreads(); }
    if (tid == 0) {
        atomicAdd(cesum, sf[0]);
        atomicAdd(selc, np + T);
    }
}

// ---------------- Kernel E: finalize ----------------
__global__ void k_final(const float* __restrict__ llsum, const int* __restrict__ Ntot,
                        const float* __restrict__ cesum, const int* __restrict__ selc,
                        float* __restrict__ out)
{
    if (blockIdx.x == 0 && threadIdx.x == 0) {
        out[0] = llsum[0] / (float)NK / (float)Ntot[0];
        out[1] = cesum[0] / (float)selc[0];
    }
}

extern "C" void kernel_launch(void* const* d_in, const int* in_sizes, int n_in,
                              void* d_out, int out_size, void* d_ws, size_t ws_size,
                              hipStream_t stream)
{
    const float* loc   = (const float*)d_in[0];
    const float* conf  = (const float*)d_in[1];
    const float* prior = (const float*)d_in[2];
    const float* gtr   = (const float*)d_in[3];
    float* out = (float*)d_out;

    char* w = (char*)d_ws;
    size_t bp = (size_t)NB * NP;
    float*    iou   = (float*)w;    w += bp * sizeof(float);
    unsigned* u     = (unsigned*)w; w += bp * sizeof(unsigned);
    float*    ce    = (float*)w;    w += bp * sizeof(float);
    // zero-initialized region (single memset): packed, cnt, llsum, cesum, selc
    unsigned long long* packed = (unsigned long long*)w; w += NB * sizeof(unsigned long long);
    int*   cnt   = (int*)w;   w += NB * sizeof(int);
    float* llsum = (float*)w; w += sizeof(float);
    float* cesum = (float*)w; w += sizeof(float);
    int*   selc  = (int*)w;   w += sizeof(int);
    size_t zbytes = (size_t)(w - (char*)packed);
    // non-initialized (always written before read)
    int* best = (int*)w; w += NB * sizeof(int);
    int* npos = (int*)w; w += NB * sizeof(int);
    int* Ntot = (int*)w; w += sizeof(int);

    hipMemsetAsync(packed, 0, zbytes, stream);

    dim3 giou((NP + 255) / 256, NB / BGROUP);
    dim3 gconf((NP + CT - 1) / CT, NB);
    k_iou   <<<giou, 256, 0, stream>>>(prior, gtr, iou, packed, cnt);
    k_mini  <<<1, 64, 0, stream>>>(packed, cnt, iou, best, npos, Ntot);
    k_conf  <<<gconf, CT, 0, stream>>>(loc, conf, prior, gtr, iou, best, u, ce, llsum);
    k_select<<<NB, 512, 0, stream>>>(u, ce, npos, cesum, selc);
    k_final <<<1, 64, 0, stream>>>(llsum, Ntot, cesum, selc, out);
}

// Round 4
// 146.769 us; speedup vs baseline: 1.1758x; 1.1758x over previous
//
#include <hip/hip_runtime.h>
#include <math.h>

#define NB 64
#define NP 8396
#define NK 6
#define NC 25
#define NPR 3                 // NEG_POS_RATIO
#define MARKER 0x007FFFFFu    // fmap(-inf); every finite mining score maps strictly above
#define NBX ((NP + 255) / 256)   // 33 x-blocks

// order-preserving float->uint map (for selecting the T-th largest)
__device__ inline unsigned fmap(float f){
    unsigned b = __float_as_uint(f);
    return (b & 0x80000000u) ? ~b : (b | 0x80000000u);
}

// ============ Kernel 1: fused IoU + softmax CE + mining key + per-block match partials ============
// grid = (NBX, NB), block = 256. No atomics; writes u, ce, ppk[b][bx], pcnt[b][bx].
__global__ __launch_bounds__(256) void k_main(
    const float* __restrict__ conf, const float* __restrict__ prior,
    const float* __restrict__ gtr,
    unsigned* __restrict__ u, float* __restrict__ ce,
    unsigned long long* __restrict__ ppk, int* __restrict__ pcnt)
{
    int b  = blockIdx.y;
    int p0 = blockIdx.x * 256;
    int t  = threadIdx.x;
    int rows = NP - p0; if (rows > 256) rows = 256;

    __shared__ float scf[256 * NC];          // 25.6 KB conf tile
    __shared__ float sgt[25];                // [cls, 24 gt coords]
    __shared__ unsigned long long wpk[4];
    __shared__ int wcnt[4];

    // coalesced float4 stage of conf tile (base offset provably 16B-aligned:
    // (b*NP + p0)*NC = b*209900 + bx*6400, both multiples of 4 floats; rows*NC % 4 == 0)
    {
        const float4* g4 = (const float4*)(conf + ((size_t)b * NP + p0) * NC);
        float4* s4 = (float4*)scf;
        int n4 = (rows * NC) >> 2;
        for (int i = t; i < n4; i += 256) s4[i] = g4[i];
    }
    if (t < 25) sgt[t] = gtr[b * 25 + t];
    __syncthreads();

    bool valid = t < rows;
    int p = p0 + t;
    float v = 0.f;
    if (valid) {
        // prior row: 6 aligned float4 (96B rows)
        float prx[24];
        const float4* pr4 = (const float4*)(prior + p * 24);
#pragma unroll
        for (int i = 0; i < 6; i++) {
            float4 q = pr4[i];
            prx[4*i+0] = q.x; prx[4*i+1] = q.y; prx[4*i+2] = q.z; prx[4*i+3] = q.w;
        }
        const float* gt = &sgt[1];
        float csum = 0.f, fsum = 0.f;
#pragma unroll
        for (int k = 0; k < NK; k++) {
            float gx0 = gt[4*k+0], gy0 = gt[4*k+1], gx1 = gt[4*k+2], gy1 = gt[4*k+3];
            float ix = fminf(prx[4*k+2], gx1) - fmaxf(prx[4*k+0], gx0);
            float iy = fminf(prx[4*k+3], gy1) - fmaxf(prx[4*k+1], gy0);
            float cross = fmaxf(ix, 0.f) * fmaxf(iy, 0.f);
            float pa = (prx[4*k+2] - prx[4*k+0]) * (prx[4*k+3] - prx[4*k+1]);
            float ga = (gx1 - gx0) * (gy1 - gy0);
            csum += cross;
            fsum += cross / (ga + pa - cross);
        }
        v = (csum > 0.f) ? (fsum * (1.f / (float)NK)) : 0.f;

        bool pos = (v >= 0.5f);      // best-prior patch handled in k_select
        int cls = (int)sgt[0];
        int tgt = pos ? cls : 0;

        const float* cf = scf + t * NC;   // stride 25 (odd) -> 2 lanes/bank, conflict-free
        float m = cf[0];
#pragma unroll
        for (int c = 1; c < NC; c++) m = fmaxf(m, cf[c]);
        float s = 0.f;
#pragma unroll
        for (int c = 0; c < NC; c++) s += expf(cf[c] - m);
        float xt = cf[tgt];
        size_t idx = (size_t)b * NP + p;
        ce[idx] = m + logf(s) - xt;
        float pt = expf(xt - m) / s;
        u[idx] = pos ? MARKER : fmap(-logf(pt + 1e-6f));
    }

    // per-wave argmax(iou, min index) + count(iou>=0.5)
    unsigned long long pk = valid
        ? (((unsigned long long)__float_as_uint(v) << 32) |
           (unsigned long long)(0xFFFFFFFFu - (unsigned)p))
        : 0ULL;
#pragma unroll
    for (int o = 32; o > 0; o >>= 1) {
        unsigned long long oth = __shfl_down(pk, o);
        if (oth > pk) pk = oth;
    }
    unsigned long long bal = __ballot(valid && v >= 0.5f);
    int lane = t & 63, wv = t >> 6;
    if (lane == 0) { wpk[wv] = pk; wcnt[wv] = __popcll(bal); }
    __syncthreads();
    if (t == 0) {
        unsigned long long m2 = wpk[0]; int c = wcnt[0];
#pragma unroll
        for (int i = 1; i < 4; i++) { if (wpk[i] > m2) m2 = wpk[i]; c += wcnt[i]; }
        ppk [b * NBX + blockIdx.x] = m2;
        pcnt[b * NBX + blockIdx.x] = c;
    }
}

// ============ Kernel 2: per-batch match finalize + byte-histogram top-T select + sums ============
// grid = NB, block = 512. Writes per-batch llb, ceb2, selb, npb (no atomics).
__global__ __launch_bounds__(512) void k_select(
    const unsigned* __restrict__ u, const float* __restrict__ ce,
    const float* __restrict__ conf, const float* __restrict__ loc,
    const float* __restrict__ prior, const float* __restrict__ gtr,
    const unsigned long long* __restrict__ ppk, const int* __restrict__ pcnt,
    float* __restrict__ llb, float* __restrict__ ceb2,
    int* __restrict__ selb, int* __restrict__ npb)
{
    int b = blockIdx.x, tid = threadIdx.x;
    const unsigned* ub = u + (size_t)b * NP;
    const float* ceb = ce + (size_t)b * NP;

    __shared__ unsigned su[NP];       // 33.6 KB
    __shared__ int hist[256];
    __shared__ int sc[512];
    __shared__ float sf[512];
    __shared__ float sl[512];
    __shared__ float sgt[25];
    __shared__ unsigned s_prefix;
    __shared__ int s_remain, s_cutoff;
    __shared__ int s_best, s_np, s_patched;
    __shared__ float s_delta;

    {   // coalesced uint4 fill (NP = 4*2099 exactly)
        const uint4* g4 = (const uint4*)ub;
        uint4* s4 = (uint4*)su;
        for (int i = tid; i < NP / 4; i += 512) s4[i] = g4[i];
    }
    if (tid >= 64 && tid < 89) sgt[tid - 64] = gtr[b * 25 + (tid - 64)];
    if (tid < 64) {   // reduce the 33 per-block partials in one wave
        unsigned long long pk = 0ULL; int c = 0;
        if (tid < NBX) { pk = ppk[b * NBX + tid]; c = pcnt[b * NBX + tid]; }
#pragma unroll
        for (int o = 32; o > 0; o >>= 1) {
            unsigned long long oth = __shfl_down(pk, o);
            if (oth > pk) pk = oth;
            c += __shfl_down(c, o);
        }
        if (tid == 0) {
            int bst = (int)(0xFFFFFFFFu - (unsigned)(pk & 0xFFFFFFFFULL));
            float vb = __uint_as_float((unsigned)(pk >> 32));
            int patched = (vb < 0.5f) ? 1 : 0;    // best prior wasn't IoU-positive
            s_best = bst; s_np = c + patched; s_patched = patched;
        }
    }
    __syncthreads();
    int best = s_best, np = s_np, patched = s_patched;
    if (tid == 0) {
        if (patched) {
            su[best] = MARKER;   // exclude from negatives, include as positive
            int cls = (int)sgt[0];
            const float* cf = conf + ((size_t)b * NP + best) * NC;
            s_delta = cf[0] - cf[cls];   // fix stored CE target 0 -> cls
        } else s_delta = 0.f;
        int T0 = NPR * np; if (T0 > NP - np) T0 = NP - np;
        s_prefix = 0u; s_remain = T0;
    }
    __syncthreads();
    float delta = s_delta;
    int T = NPR * np; if (T > NP - np) T = NP - np;

    // 4 byte-levels, MSB first: exact T-th largest key
#pragma unroll
    for (int level = 0; level < 4; ++level) {
        const int shift = 24 - 8 * level;
        if (tid < 256) hist[tid] = 0;
        __syncthreads();
        unsigned pref = s_prefix;
        int remain = s_remain;
        for (int p = tid; p < NP; p += 512) {
            unsigned v = su[p];
            bool match = (level == 0) || ((v >> (shift + 8)) == pref);
            if (match) atomicAdd(&hist[(v >> shift) & 255], 1);
        }
        __syncthreads();
        if (tid < 64) {   // single-wave suffix scan, lane owns bins [4t..4t+3]
            int h0 = hist[4*tid+0], h1 = hist[4*tid+1], h2 = hist[4*tid+2], h3 = hist[4*tid+3];
            int locs = h0 + h1 + h2 + h3;
            int run = locs;
#pragma unroll
            for (int o = 1; o < 64; o <<= 1) {
                int oth = __shfl_down(run, o);
                if (tid + o < 64) run += oth;
            }
            int suff = run - locs;
            int hh[4] = {h0, h1, h2, h3};
#pragma unroll
            for (int j = 3; j >= 0; --j) {
                int above = suff, hj = hh[j];
                if (above < remain && above + hj >= remain) {   // exactly one (tid,j)
                    s_prefix = (pref << 8) | (unsigned)(4*tid + j);
                    s_remain = remain - above;
                }
                suff += hj;
            }
        }
        __syncthreads();
    }
    unsigned thr = s_prefix;
    int needed = s_remain;

    // boundary ties
    int tc = 0;
    for (int p = tid; p < NP; p += 512) tc += (su[p] == thr) ? 1 : 0;
    sc[tid] = tc;
    __syncthreads();
    for (int s = 256; s > 0; s >>= 1) { if (tid < s) sc[tid] += sc[tid + s]; __syncthreads(); }
    if (tid == 0) {
        if (sc[0] <= needed) s_cutoff = NP;
        else {   // rare: stable-by-index prefix of ties
            int c2 = 0, cut = -1;
            for (int p = 0; p < NP; ++p)
                if (su[p] == thr) { if (++c2 == needed) { cut = p; break; } }
            s_cutoff = cut;
        }
    }
    __syncthreads();
    int cutoff = s_cutoff;

    // CE sum over selected + smooth-L1 over positives (MARKER scan)
    float sum = 0.f, ll = 0.f;
    for (int p = tid; p < NP; p += 512) {
        unsigned v = su[p];
        if (v == MARKER) {
            sum += ceb[p] + ((patched && p == best) ? delta : 0.f);
            const float* pr = prior + p * 24;
            const float* gt = &sgt[1];
            const float* lp = loc + ((size_t)b * NP + p) * 24;
            float s1 = 0.f;
#pragma unroll
            for (int k = 0; k < NK; k++) {
                float px0 = pr[4*k+0], py0 = pr[4*k+1], px1 = pr[4*k+2], py1 = pr[4*k+3];
                float gx0 = gt[4*k+0], gy0 = gt[4*k+1], gx1 = gt[4*k+2], gy1 = gt[4*k+3];
                float pcx = (px0 + px1) * 0.5f, pcy = (py0 + py1) * 0.5f;
                float pw = px1 - px0, ph = py1 - py0;
                float gcx = (gx0 + gx1) * 0.5f, gcy = (gy0 + gy1) * 0.5f;
                float gw = gx1 - gx0, gh = gy1 - gy0;
                float e0 = ((gcx - pcx) / pw) * 10.f;
                float e1 = ((gcy - pcy) / ph) * 10.f;
                float e2 = logf(gw / pw) * 5.f;
                float e3 = logf(gh / ph) * 5.f;
                float d;
                d = fabsf(lp[4*k+0] - e0); s1 += (d < 1.f) ? 0.5f*d*d : d - 0.5f;
                d = fabsf(lp[4*k+1] - e1); s1 += (d < 1.f) ? 0.5f*d*d : d - 0.5f;
                d = fabsf(lp[4*k+2] - e2); s1 += (d < 1.f) ? 0.5f*d*d : d - 0.5f;
                d = fabsf(lp[4*k+3] - e3); s1 += (d < 1.f) ? 0.5f*d*d : d - 0.5f;
            }
            ll += s1;
        } else if (v > thr || (v == thr && p <= cutoff)) {
            sum += ceb[p];
        }
    }
    sf[tid] = sum; sl[tid] = ll;
    __syncthreads();
    for (int s = 256; s > 0; s >>= 1) {
        if (tid < s) { sf[tid] += sf[tid + s]; sl[tid] += sl[tid + s]; }
        __syncthreads();
    }
    if (tid == 0) {
        llb[b]  = sl[0];
        ceb2[b] = sf[0];
        selb[b] = np + T;
        npb[b]  = np;
    }
}

// ============ Kernel 3: final reduction over batches ============
__global__ void k_final(const float* __restrict__ llb, const float* __restrict__ ceb2,
                        const int* __restrict__ selb, const int* __restrict__ npb,
                        float* __restrict__ out)
{
    int t = threadIdx.x;   // 64 = NB
    float ll = llb[t], cs = ceb2[t];
    int sel = selb[t], np = npb[t];
#pragma unroll
    for (int o = 32; o > 0; o >>= 1) {
        ll  += __shfl_down(ll, o);
        cs  += __shfl_down(cs, o);
        sel += __shfl_down(sel, o);
        np  += __shfl_down(np, o);
    }
    if (t == 0) {
        out[0] = ll / (float)NK / (float)np;
        out[1] = cs / (float)sel;
    }
}

extern "C" void kernel_launch(void* const* d_in, const int* in_sizes, int n_in,
                              void* d_out, int out_size, void* d_ws, size_t ws_size,
                              hipStream_t stream)
{
    const float* loc   = (const float*)d_in[0];
    const float* conf  = (const float*)d_in[1];
    const float* prior = (const float*)d_in[2];
    const float* gtr   = (const float*)d_in[3];
    float* out = (float*)d_out;

    char* w = (char*)d_ws;
    size_t bp = (size_t)NB * NP;
    unsigned* u  = (unsigned*)w; w += bp * sizeof(unsigned);
    float*    ce = (float*)w;    w += bp * sizeof(float);
    unsigned long long* ppk = (unsigned long long*)w; w += (size_t)NB * NBX * sizeof(unsigned long long);
    int*   pcnt = (int*)w;   w += (size_t)NB * NBX * sizeof(int);
    float* llb  = (float*)w; w += NB * sizeof(float);
    float* ceb2 = (float*)w; w += NB * sizeof(float);
    int*   selb = (int*)w;   w += NB * sizeof(int);
    int*   npb  = (int*)w;   w += NB * sizeof(int);

    dim3 gmain(NBX, NB);
    k_main  <<<gmain, 256, 0, stream>>>(conf, prior, gtr, u, ce, ppk, pcnt);
    k_select<<<NB, 512, 0, stream>>>(u, ce, conf, loc, prior, gtr, ppk, pcnt,
                                     llb, ceb2, selb, npb);
    k_final <<<1, 64, 0, stream>>>(llb, ceb2, selb, npb, out);
}

// Round 5
// 141.366 us; speedup vs baseline: 1.2207x; 1.0382x over previous
//
#include <hip/hip_runtime.h>
#include <math.h>

#define NB 64
#define NP 8396
#define NK 6
#define NC 25
#define NPR 3                    // NEG_POS_RATIO
#define MARKER 0x007FFFFFu       // fmap(-inf); every finite mining score maps strictly above
#define NBX ((NP + 255) / 256)   // 33 x-blocks in k_main
#define ST 1024                  // k_select block size

// order-preserving float->uint map (for selecting the T-th largest)
__device__ inline unsigned fmap(float f){
    unsigned b = __float_as_uint(f);
    return (b & 0x80000000u) ? ~b : (b | 0x80000000u);
}
__device__ inline float unfmap(unsigned v){
    return (v & 0x80000000u) ? __uint_as_float(v & 0x7FFFFFFFu)
                             : __uint_as_float(~v);
}

// softmax cross-entropy with target tgt over a 25-float row (global gather; rare)
__device__ inline float ce_row(const float* __restrict__ cf, int tgt){
    float m = cf[0];
#pragma unroll
    for (int c = 1; c < NC; c++) m = fmaxf(m, cf[c]);
    float s = 0.f;
#pragma unroll
    for (int c = 0; c < NC; c++) s += expf(cf[c] - m);
    return m + logf(s) - cf[tgt];
}

// ============ Kernel 1: fused IoU + mining key + per-block match partials ============
// grid = (NBX, NB), block = 256. No CE computation/storage. Block (0,0) zero-inits
// the device-scope accumulators (safe: consumed only by kernel 2, stream-ordered).
__global__ __launch_bounds__(256) void k_main(
    const float* __restrict__ conf, const float* __restrict__ prior,
    const float* __restrict__ gtr,
    unsigned* __restrict__ u,
    unsigned long long* __restrict__ ppk, int* __restrict__ pcnt,
    float* __restrict__ acc_ll, float* __restrict__ acc_ce,
    int* __restrict__ acc_sel, int* __restrict__ acc_np, int* __restrict__ done)
{
    int b  = blockIdx.y;
    int p0 = blockIdx.x * 256;
    int t  = threadIdx.x;
    if (blockIdx.x == 0 && b == 0 && t == 0) {
        atomicExch(acc_ll, 0.f); atomicExch(acc_ce, 0.f);
        atomicExch(acc_sel, 0);  atomicExch(acc_np, 0); atomicExch(done, 0);
    }
    int rows = NP - p0; if (rows > 256) rows = 256;

    __shared__ float scf[256 * NC];          // 25.6 KB conf tile
    __shared__ float sgt[25];
    __shared__ unsigned long long wpk[4];
    __shared__ int wcnt[4];

    {   // coalesced float4 stage (base offset provably 16B-aligned; rows*NC % 4 == 0)
        const float4* g4 = (const float4*)(conf + ((size_t)b * NP + p0) * NC);
        float4* s4 = (float4*)scf;
        int n4 = (rows * NC) >> 2;
        for (int i = t; i < n4; i += 256) s4[i] = g4[i];
    }
    if (t < 25) sgt[t] = gtr[b * 25 + t];
    __syncthreads();

    bool valid = t < rows;
    int p = p0 + t;
    float v = 0.f;
    if (valid) {
        float prx[24];
        const float4* pr4 = (const float4*)(prior + p * 24);   // 96B rows, aligned
#pragma unroll
        for (int i = 0; i < 6; i++) {
            float4 q = pr4[i];
            prx[4*i+0] = q.x; prx[4*i+1] = q.y; prx[4*i+2] = q.z; prx[4*i+3] = q.w;
        }
        const float* gt = &sgt[1];
        float csum = 0.f, fsum = 0.f;
#pragma unroll
        for (int k = 0; k < NK; k++) {
            float gx0 = gt[4*k+0], gy0 = gt[4*k+1], gx1 = gt[4*k+2], gy1 = gt[4*k+3];
            float ix = fminf(prx[4*k+2], gx1) - fmaxf(prx[4*k+0], gx0);
            float iy = fminf(prx[4*k+3], gy1) - fmaxf(prx[4*k+1], gy0);
            float cross = fmaxf(ix, 0.f) * fmaxf(iy, 0.f);
            float pa = (prx[4*k+2] - prx[4*k+0]) * (prx[4*k+3] - prx[4*k+1]);
            float ga = (gx1 - gx0) * (gy1 - gy0);
            csum += cross;
            fsum += cross / (ga + pa - cross);
        }
        v = (csum > 0.f) ? (fsum * (1.f / (float)NK)) : 0.f;

        size_t idx = (size_t)b * NP + p;
        if (v >= 0.5f) {
            u[idx] = MARKER;           // positive (best-prior patch done in k_select)
        } else {
            const float* cf = scf + t * NC;   // stride 25 -> conflict-free
            float m = cf[0];
#pragma unroll
            for (int c = 1; c < NC; c++) m = fmaxf(m, cf[c]);
            float s = 0.f;
#pragma unroll
            for (int c = 0; c < NC; c++) s += expf(cf[c] - m);
            float p0f = expf(cf[0] - m) / s;
            u[idx] = fmap(-logf(p0f + 1e-6f));
        }
    }

    // per-wave argmax(iou, min index) + count(iou>=0.5)
    unsigned long long pk = valid
        ? (((unsigned long long)__float_as_uint(v) << 32) |
           (unsigned long long)(0xFFFFFFFFu - (unsigned)p))
        : 0ULL;
#pragma unroll
    for (int o = 32; o > 0; o >>= 1) {
        unsigned long long oth = __shfl_down(pk, o);
        if (oth > pk) pk = oth;
    }
    unsigned long long bal = __ballot(valid && v >= 0.5f);
    int lane = t & 63, wv = t >> 6;
    if (lane == 0) { wpk[wv] = pk; wcnt[wv] = __popcll(bal); }
    __syncthreads();
    if (t == 0) {
        unsigned long long m2 = wpk[0]; int c = wcnt[0];
#pragma unroll
        for (int i = 1; i < 4; i++) { if (wpk[i] > m2) m2 = wpk[i]; c += wcnt[i]; }
        ppk [b * NBX + blockIdx.x] = m2;
        pcnt[b * NBX + blockIdx.x] = c;
    }
}

// ============ Kernel 2: match finalize + byte-histogram top-T select + all sums + finalize ============
// grid = NB, block = ST(=1024). Last-done block computes the two outputs.
__global__ __launch_bounds__(ST) void k_select(
    const unsigned* __restrict__ u, const float* __restrict__ conf,
    const float* __restrict__ loc, const float* __restrict__ prior,
    const float* __restrict__ gtr,
    const unsigned long long* __restrict__ ppk, const int* __restrict__ pcnt,
    float* __restrict__ acc_ll, float* __restrict__ acc_ce,
    int* __restrict__ acc_sel, int* __restrict__ acc_np, int* __restrict__ done,
    float* __restrict__ out)
{
    int b = blockIdx.x, tid = threadIdx.x;
    const unsigned* ub = u + (size_t)b * NP;

    __shared__ unsigned su[NP];       // 33.6 KB
    __shared__ int hist[256];
    __shared__ float sgt[25];
    __shared__ unsigned s_prefix;
    __shared__ int s_remain, s_cutoff;
    __shared__ int s_best, s_np, s_patched;
    __shared__ float redf[ST/64], redl[ST/64];
    __shared__ int   redi[ST/64];

    {   // coalesced uint4 fill (NP = 4*2099 exactly)
        const uint4* g4 = (const uint4*)ub;
        uint4* s4 = (uint4*)su;
        for (int i = tid; i < NP / 4; i += ST) s4[i] = g4[i];
    }
    if (tid >= 64 && tid < 89) sgt[tid - 64] = gtr[b * 25 + (tid - 64)];
    if (tid < 64) {   // reduce the 33 per-block partials in one wave
        unsigned long long pk = 0ULL; int c = 0;
        if (tid < NBX) { pk = ppk[b * NBX + tid]; c = pcnt[b * NBX + tid]; }
#pragma unroll
        for (int o = 32; o > 0; o >>= 1) {
            unsigned long long oth = __shfl_down(pk, o);
            if (oth > pk) pk = oth;
            c += __shfl_down(c, o);
        }
        if (tid == 0) {
            int bst = (int)(0xFFFFFFFFu - (unsigned)(pk & 0xFFFFFFFFULL));
            float vb = __uint_as_float((unsigned)(pk >> 32));
            int patched = (vb < 0.5f) ? 1 : 0;
            s_best = bst; s_np = c + patched; s_patched = patched;
        }
    }
    __syncthreads();
    int best = s_best, np = s_np;
    if (tid == 0) {
        if (s_patched) su[best] = MARKER;   // promote best prior to positive
        int T0 = NPR * np; if (T0 > NP - np) T0 = NP - np;
        s_prefix = 0u; s_remain = T0;
    }
    __syncthreads();
    int T = NPR * np; if (T > NP - np) T = NP - np;

    const int ITERS = (NP + ST - 1) / ST;   // 9, wave-uniform
    for (int level = 0; level < 4; ++level) {
        const int shift = 24 - 8 * level;
        if (tid < 256) hist[tid] = 0;
        __syncthreads();
        unsigned pref = s_prefix;
        int remain = s_remain;
        for (int it = 0; it < ITERS; ++it) {
            int p = tid + it * ST;
            bool act = (p < NP);
            unsigned key = act ? su[p] : 0u;
            if (level > 0) act = act && ((key >> (shift + 8)) == pref);
            unsigned bin = (key >> shift) & 255u;
            if (level == 0) {
                // mining scores concentrate in ~1-2 top-byte bins: wave-dedup the adds
                bool fin = !act;
                while (true) {
                    unsigned long long mask = __ballot(!fin);
                    if (!mask) break;
                    int leader = __ffsll(mask) - 1;
                    unsigned lbin = __shfl(bin, leader);
                    bool same = (!fin) && (bin == lbin);
                    unsigned long long sm = __ballot(same);
                    if ((tid & 63) == leader) atomicAdd(&hist[lbin], (int)__popcll(sm));
                    if (same) fin = true;
                }
            } else if (act) {
                atomicAdd(&hist[bin], 1);
            }
        }
        __syncthreads();
        if (tid < 64) {   // single-wave suffix scan, lane owns bins [4t..4t+3]
            int h0 = hist[4*tid+0], h1 = hist[4*tid+1], h2 = hist[4*tid+2], h3 = hist[4*tid+3];
            int locs = h0 + h1 + h2 + h3;
            int run = locs;
#pragma unroll
            for (int o = 1; o < 64; o <<= 1) {
                int oth = __shfl_down(run, o);
                if (tid + o < 64) run += oth;
            }
            int suff = run - locs;
            int hh[4] = {h0, h1, h2, h3};
#pragma unroll
            for (int j = 3; j >= 0; --j) {
                int above = suff, hj = hh[j];
                if (above < remain && above + hj >= remain) {   // exactly one (tid,j)
                    s_prefix = (pref << 8) | (unsigned)(4*tid + j);
                    s_remain = remain - above;
                }
                suff += hj;
            }
        }
        __syncthreads();
    }
    unsigned thr = s_prefix;
    int needed = s_remain;

    int lane = tid & 63, wv = tid >> 6;
    // boundary ties
    int tc = 0;
    for (int p = tid; p < NP; p += ST) tc += (su[p] == thr) ? 1 : 0;
#pragma unroll
    for (int o = 32; o > 0; o >>= 1) tc += __shfl_down(tc, o);
    if (lane == 0) redi[wv] = tc;
    __syncthreads();
    if (tid == 0) {
        int tot = 0;
#pragma unroll
        for (int i = 0; i < ST/64; i++) tot += redi[i];
        if (tot <= needed) s_cutoff = NP;
        else {   // rare: stable-by-index prefix of ties
            int c2 = 0, cut = -1;
            for (int p = 0; p < NP; ++p)
                if (su[p] == thr) { if (++c2 == needed) { cut = p; break; } }
            s_cutoff = cut;
        }
    }
    __syncthreads();
    int cutoff = s_cutoff;

    // CE over positives (recomputed, target=cls) + derived CE over selected negatives
    // + smooth-L1 over positives
    int cls = (int)sgt[0];
    float cesum = 0.f, ll = 0.f;
    for (int p = tid; p < NP; p += ST) {
        unsigned v = su[p];
        if (v == MARKER) {
            cesum += ce_row(conf + ((size_t)b * NP + p) * NC, cls);
            const float* pr = prior + p * 24;
            const float* gt = &sgt[1];
            const float* lp = loc + ((size_t)b * NP + p) * 24;
            float s1 = 0.f;
#pragma unroll
            for (int k = 0; k < NK; k++) {
                float px0 = pr[4*k+0], py0 = pr[4*k+1], px1 = pr[4*k+2], py1 = pr[4*k+3];
                float gx0 = gt[4*k+0], gy0 = gt[4*k+1], gx1 = gt[4*k+2], gy1 = gt[4*k+3];
                float pcx = (px0 + px1) * 0.5f, pcy = (py0 + py1) * 0.5f;
                float pw = px1 - px0, ph = py1 - py0;
                float gcx = (gx0 + gx1) * 0.5f, gcy = (gy0 + gy1) * 0.5f;
                float gw = gx1 - gx0, gh = gy1 - gy0;
                float e0 = ((gcx - pcx) / pw) * 10.f;
                float e1 = ((gcy - pcy) / ph) * 10.f;
                float e2 = logf(gw / pw) * 5.f;
                float e3 = logf(gh / ph) * 5.f;
                float d;
                d = fabsf(lp[4*k+0] - e0); s1 += (d < 1.f) ? 0.5f*d*d : d - 0.5f;
                d = fabsf(lp[4*k+1] - e1); s1 += (d < 1.f) ? 0.5f*d*d : d - 0.5f;
                d = fabsf(lp[4*k+2] - e2); s1 += (d < 1.f) ? 0.5f*d*d : d - 0.5f;
                d = fabsf(lp[4*k+3] - e3); s1 += (d < 1.f) ? 0.5f*d*d : d - 0.5f;
            }
            ll += s1;
        } else if (v > thr || (v == thr && p <= cutoff)) {
            float tl = unfmap(v);                      // = -log(p0 + 1e-6)
            cesum += -logf(expf(-tl) - 1e-6f);         // = -log(p0) exactly (to fp rounding)
        }
    }
#pragma unroll
    for (int o = 32; o > 0; o >>= 1) {
        cesum += __shfl_down(cesum, o);
        ll    += __shfl_down(ll, o);
    }
    if (lane == 0) { redf[wv] = cesum; redl[wv] = ll; }
    __syncthreads();
    if (tid == 0) {
        float cs = 0.f, l2 = 0.f;
#pragma unroll
        for (int i = 0; i < ST/64; i++) { cs += redf[i]; l2 += redl[i]; }
        atomicAdd(acc_ce, cs);
        atomicAdd(acc_ll, l2);
        atomicAdd(acc_sel, np + T);
        atomicAdd(acc_np, np);
        __threadfence();
        int old = atomicAdd(done, 1);
        if (old == NB - 1) {       // last block finalizes (all reads via device atomics)
            __threadfence();
            float allce = atomicAdd(acc_ce, 0.f);
            float allll = atomicAdd(acc_ll, 0.f);
            int sel = atomicAdd(acc_sel, 0);
            int npt = atomicAdd(acc_np, 0);
            out[0] = allll / (float)NK / (float)npt;
            out[1] = allce / (float)sel;
        }
    }
}

extern "C" void kernel_launch(void* const* d_in, const int* in_sizes, int n_in,
                              void* d_out, int out_size, void* d_ws, size_t ws_size,
                              hipStream_t stream)
{
    const float* loc   = (const float*)d_in[0];
    const float* conf  = (const float*)d_in[1];
    const float* prior = (const float*)d_in[2];
    const float* gtr   = (const float*)d_in[3];
    float* out = (float*)d_out;

    char* w = (char*)d_ws;
    size_t bp = (size_t)NB * NP;
    unsigned* u = (unsigned*)w; w += bp * sizeof(unsigned);
    unsigned long long* ppk = (unsigned long long*)w; w += (size_t)NB * NBX * sizeof(unsigned long long);
    int*   pcnt   = (int*)w;   w += (size_t)NB * NBX * sizeof(int);
    float* acc_ll = (float*)w; w += sizeof(float);
    float* acc_ce = (float*)w; w += sizeof(float);
    int*   acc_sel= (int*)w;   w += sizeof(int);
    int*   acc_np = (int*)w;   w += sizeof(int);
    int*   done   = (int*)w;   w += sizeof(int);

    dim3 gmain(NBX, NB);
    k_main  <<<gmain, 256, 0, stream>>>(conf, prior, gtr, u, ppk, pcnt,
                                        acc_ll, acc_ce, acc_sel, acc_np, done);
    k_select<<<NB, ST, 0, stream>>>(u, conf, loc, prior, gtr, ppk, pcnt,
                                    acc_ll, acc_ce, acc_sel, acc_np, done, out);
}